// Round 5
// baseline (445.123 us; speedup 1.0000x reference)
//
#include <hip/hip_runtime.h>
#include <hip/hip_bf16.h>

#define NN 1024
#define DD 128
#define KK 16
#define SPLITK 8

typedef __attribute__((ext_vector_type(4))) float f32x4;
typedef __attribute__((ext_vector_type(8))) short bf16x8;
typedef __attribute__((ext_vector_type(4))) unsigned int u32x4;
typedef __attribute__((ext_vector_type(4))) unsigned short u16x4;

static __device__ __forceinline__ unsigned short f2bf(float x) {
  union { __hip_bfloat16 h; unsigned short u; } v;
  v.h = __float2bfloat16(x);
  return v.u;
}

// ---------------------------------------------------------------------------
// Kernel 1: edge features -> A2[(i*16+k)][j] = rbf(i,j,k)*w(i,j)  (bf16)
// tail blocks: transpose-cast embed->hTa, w1->w1T, w2->w2T; zero cnt[192]
// ---------------------------------------------------------------------------
__global__ __launch_bounds__(256) void edge_setup(
    const float* __restrict__ r, const float* __restrict__ embed,
    const float* __restrict__ w1, const float* __restrict__ w2,
    unsigned short* __restrict__ A2, unsigned short* __restrict__ hTa,
    unsigned short* __restrict__ w1T, unsigned short* __restrict__ w2T,
    int* __restrict__ cnt)
{
  int b = blockIdx.x;
  if (b < 4096) {
    int idx = b * 256 + threadIdx.x;
    int i = idx >> 10, j = idx & (NN - 1);
    float dx = r[i*3+0] - r[j*3+0];
    float dy = r[i*3+1] - r[j*3+1];
    float dz = r[i*3+2] - r[j*3+2];
    float d2 = dx*dx + dy*dy + dz*dz;
    float vals[KK];
    bool on = (i != j) && (d2 < 4.0f);
    if (on) {
      float dist = sqrtf(d2);
      float w  = 0.5f * (__cosf(1.57079632679f * dist) + 1.0f);  // cos(pi*d/2)
      float E0 = __expf(-10.0f * d2);
      float q  = __expf(2.66666667f * dist);      // exp(20*(2/15)*d)
      float u  = __expf(-0.17777778f);            // exp(-10*(2/15)^2)
      float u2 = u * u;
      float p = 1.0f, c = 1.0f, s = u;
      #pragma unroll
      for (int k = 0; k < KK; ++k) {
        vals[k] = w * (E0 * p) * c;   // = w * exp(-10*(d - k*2/15)^2)
        p *= q;
        c *= s;
        s *= u2;
      }
    } else {
      #pragma unroll
      for (int k = 0; k < KK; ++k) vals[k] = 0.0f;
    }
    #pragma unroll
    for (int k = 0; k < KK; ++k)
      A2[(size_t)(i * KK + k) * NN + j] = f2bf(vals[k]);
  } else if (b == 4096 + 56) {
    if (threadIdx.x < 192) cnt[threadIdx.x] = 0;
  } else {
    // transpose-cast jobs, 64x64 tiles via LDS
    int t = b - 4096;
    const float* src; unsigned short* dst; int R, r0, c0;
    if (t < 32)      { src = embed; dst = hTa; R = NN;  int u = t;      r0 = (u>>1)*64; c0 = (u&1)*64; }
    else if (t < 44) { src = w1;    dst = w1T; R = 384; int u = t - 32; r0 = (u>>1)*64; c0 = (u&1)*64; }
    else             { src = w2;    dst = w2T; R = 384; int u = t - 44; r0 = (u>>1)*64; c0 = (u&1)*64; }
    __shared__ float Ls[64][65];
    #pragma unroll
    for (int it = 0; it < 16; ++it) {
      int idx = it * 256 + threadIdx.x;
      int rr = idx >> 6, cc = idx & 63;
      Ls[rr][cc] = src[(size_t)(r0 + rr) * DD + c0 + cc];
    }
    __syncthreads();
    #pragma unroll
    for (int it = 0; it < 16; ++it) {
      int idx = it * 256 + threadIdx.x;
      int oc = idx >> 6, orr = idx & 63;       // out row = c0+oc, out col = r0+orr
      dst[(size_t)(c0 + oc) * R + r0 + orr] = f2bf(Ls[orr][oc]);
    }
  }
}

// ---------------------------------------------------------------------------
// Kernel 2 (per layer): gemm + fused split-K-fixup MLP.
// Grid 1024 = 128 M-tiles x split-K 8. Phase 1 = verified r4 gemm_agg body,
// writes partial plane. Then fence + counter; the 16th arrival for a 16-node
// tile (2 M-tiles x 8 ks) runs the verified MLP body for those 16 rows.
// Deadlock-free: no WG ever waits.
// ---------------------------------------------------------------------------
union SharedU {
  struct { unsigned short As[128][40]; unsigned short Bs[128][40]; } g;
  struct { unsigned short Xs[16][136]; unsigned short Ws[128][136]; } m;
};

__global__ __launch_bounds__(256) void gemm_fused(
    const unsigned short* __restrict__ A2,
    const unsigned short* __restrict__ hT,     // input transpose (ping)
    const float* __restrict__ wf,              // layer slice [16][128]
    float* __restrict__ aggbase,               // SPLITK planes [1024][128]
    int* __restrict__ cnt,                     // 64 counters (this layer)
    const float* __restrict__ hprev,           // residual input f32
    const unsigned short* __restrict__ w1T,    // layer col-offset, stride 384
    const float* __restrict__ b1,
    const unsigned short* __restrict__ w2T,
    const float* __restrict__ b2,
    float* __restrict__ hnext,                 // f32 h out (non-final)
    unsigned short* __restrict__ hTnext,       // transpose out (pong, non-final)
    float* __restrict__ outf)                  // d_out (final)
{
  __shared__ SharedU sh;
  __shared__ int go;
  int wg = blockIdx.x;
  int mt = wg >> 3;                          // 0..127
  int ks = wg & 7;
  int mbase = mt * 128;
  int tid = threadIdx.x;
  int w = tid >> 6, lane = tid & 63;
  int wm = w >> 1, wd = w & 1;
  int lg = lane >> 4, l16 = lane & 15;

  // ================= Phase 1: split-K GEMM partial =================
  {
    f32x4 acc[4][4];
    #pragma unroll
    for (int a = 0; a < 4; ++a)
      #pragma unroll
      for (int bq = 0; bq < 4; ++bq) acc[a][bq] = (f32x4){0.f, 0.f, 0.f, 0.f};

    int jbase = ks * 128;
    for (int s = 0; s < 4; ++s) {
      int j0 = jbase + s * 32;
      __syncthreads();
      #pragma unroll
      for (int it = 0; it < 2; ++it) {
        int c = tid + it * 256;
        int row = c >> 2, col8 = (c & 3) * 8;
        u32x4 va = *(const u32x4*)(A2 + (size_t)(mbase + row) * NN + j0 + col8);
        *(u32x4*)(&sh.g.As[row][col8]) = va;
        u32x4 vb = *(const u32x4*)(hT + (size_t)row * NN + j0 + col8);
        *(u32x4*)(&sh.g.Bs[row][col8]) = vb;
      }
      __syncthreads();
      bf16x8 af[4], bfr[4];
      #pragma unroll
      for (int f = 0; f < 4; ++f) {
        af[f]  = *(const bf16x8*)(&sh.g.As[wm*64 + f*16 + l16][lg*8]);
        bfr[f] = *(const bf16x8*)(&sh.g.Bs[wd*64 + f*16 + l16][lg*8]);
      }
      #pragma unroll
      for (int fm = 0; fm < 4; ++fm)
        #pragma unroll
        for (int fd = 0; fd < 4; ++fd)
          acc[fm][fd] = __builtin_amdgcn_mfma_f32_16x16x32_bf16(
              af[fm], bfr[fd], acc[fm][fd], 0, 0, 0);
    }

    // epilogue: partial[node][d] = sum_k wf[k][d] * T[(node,k)][d]
    float* aggp = aggbase + (size_t)ks * NN * DD;
    float wfv[4][4];
    #pragma unroll
    for (int fd = 0; fd < 4; ++fd) {
      int d = wd*64 + fd*16 + l16;
      #pragma unroll
      for (int rr = 0; rr < 4; ++rr)
        wfv[fd][rr] = wf[(lg*4 + rr) * DD + d];
    }
    #pragma unroll
    for (int fm = 0; fm < 4; ++fm) {
      int node = mt * 8 + wm * 4 + fm;
      #pragma unroll
      for (int fd = 0; fd < 4; ++fd) {
        int d = wd*64 + fd*16 + l16;
        float sum = 0.f;
        #pragma unroll
        for (int rr = 0; rr < 4; ++rr)
          sum += acc[fm][fd][rr] * wfv[fd][rr];
        sum += __shfl_xor(sum, 16, 64);
        sum += __shfl_xor(sum, 32, 64);
        if (lg == 0) aggp[(size_t)node * DD + d] = sum;
      }
    }
  }

  // ================= fixup handoff =================
  __threadfence();                 // release: partials -> device visible
  __syncthreads();                 // all threads' stores fenced; LDS reuse safe
  if (tid == 0) go = (atomicAdd(&cnt[mt >> 1], 1) == 15);
  __syncthreads();
  if (!go) return;
  __threadfence();                 // acquire: see other WGs' partials

  // ================= Phase 2: MLP for rows0..+16 (last arriver) =============
  int rows0 = (mt >> 1) * 16;

  // stage X = bf16(sum of SPLITK agg planes): 16x128
  #pragma unroll
  for (int it = 0; it < 2; ++it) {
    int c = tid + it * 256;                   // 512 chunks of 4 floats
    int row = c >> 5, off = (c & 31) * 4;
    size_t g = (size_t)(rows0 + row) * DD + off;
    f32x4 s0 = *(const f32x4*)(aggbase + g);
    #pragma unroll
    for (int p = 1; p < SPLITK; ++p) {
      f32x4 vp = *(const f32x4*)(aggbase + (size_t)p * NN * DD + g);
      s0 += vp;
    }
    u16x4 t4;
    #pragma unroll
    for (int e = 0; e < 4; ++e) t4[e] = f2bf(s0[e]);
    *(u16x4*)(&sh.m.Xs[row][off]) = t4;
  }
  // stage W1: 128x128
  #pragma unroll
  for (int it = 0; it < 8; ++it) {
    int c = tid + it * 256;
    int row = c >> 4, off8 = (c & 15) * 8;
    u32x4 v = *(const u32x4*)(w1T + (size_t)row * 384 + off8);
    *(u32x4*)(&sh.m.Ws[row][off8]) = v;
  }
  __syncthreads();

  // GEMM1: wave w -> out cols [w*32, w*32+32)
  f32x4 acc1[2];
  acc1[0] = (f32x4){0.f,0.f,0.f,0.f}; acc1[1] = (f32x4){0.f,0.f,0.f,0.f};
  #pragma unroll
  for (int s = 0; s < 4; ++s) {
    bf16x8 a = *(const bf16x8*)(&sh.m.Xs[l16][s*32 + lg*8]);
    #pragma unroll
    for (int f = 0; f < 2; ++f) {
      bf16x8 bb = *(const bf16x8*)(&sh.m.Ws[(w*2+f)*16 + l16][s*32 + lg*8]);
      acc1[f] = __builtin_amdgcn_mfma_f32_16x16x32_bf16(a, bb, acc1[f], 0, 0, 0);
    }
  }
  __syncthreads();   // all GEMM1 LDS reads done

  // silu -> Xs (overwrite), restage W2 -> Ws
  #pragma unroll
  for (int f = 0; f < 2; ++f) {
    int d = w*32 + f*16 + l16;
    float bb1 = b1[d];
    #pragma unroll
    for (int rr = 0; rr < 4; ++rr) {
      float x = acc1[f][rr] + bb1;
      float sv = x / (1.0f + __expf(-x));
      sh.m.Xs[lg*4 + rr][d] = f2bf(sv);
    }
  }
  #pragma unroll
  for (int it = 0; it < 8; ++it) {
    int c = tid + it * 256;
    int row = c >> 4, off8 = (c & 15) * 8;
    u32x4 v = *(const u32x4*)(w2T + (size_t)row * 384 + off8);
    *(u32x4*)(&sh.m.Ws[row][off8]) = v;
  }
  __syncthreads();

  // GEMM2
  f32x4 acc2[2];
  acc2[0] = (f32x4){0.f,0.f,0.f,0.f}; acc2[1] = (f32x4){0.f,0.f,0.f,0.f};
  #pragma unroll
  for (int s = 0; s < 4; ++s) {
    bf16x8 a = *(const bf16x8*)(&sh.m.Xs[l16][s*32 + lg*8]);
    #pragma unroll
    for (int f = 0; f < 2; ++f) {
      bf16x8 bb = *(const bf16x8*)(&sh.m.Ws[(w*2+f)*16 + l16][s*32 + lg*8]);
      acc2[f] = __builtin_amdgcn_mfma_f32_16x16x32_bf16(a, bb, acc2[f], 0, 0, 0);
    }
  }

  // epilogue: v = acc2 + b2 + hprev
  float vv[2][4];
  bool fin = (outf != nullptr);
  #pragma unroll
  for (int f = 0; f < 2; ++f) {
    int d = w*32 + f*16 + l16;
    float bb2 = b2[d];
    #pragma unroll
    for (int rr = 0; rr < 4; ++rr) {
      int row = rows0 + lg*4 + rr;
      float v = acc2[f][rr] + bb2 + hprev[(size_t)row * DD + d];
      vv[f][rr] = v;
      if (fin) outf[(size_t)row * DD + d] = v;
      else     hnext[(size_t)row * DD + d] = v;
    }
  }
  if (!fin) {
    __syncthreads();   // GEMM2 LDS reads done before Ws reuse
    // transposed tile into Ws: [d][m_local 0..15]
    #pragma unroll
    for (int f = 0; f < 2; ++f) {
      int d = w*32 + f*16 + l16;
      #pragma unroll
      for (int rr = 0; rr < 4; ++rr)
        sh.m.Ws[d][lg*4 + rr] = f2bf(vv[f][rr]);
    }
    __syncthreads();
    // copy out: hTnext[d][rows0..+16], one u32x4 per thread
    int d = tid >> 1, off = (tid & 1) * 8;
    u32x4 v = *(const u32x4*)(&sh.m.Ws[d][off]);
    *(u32x4*)(hTnext + (size_t)d * NN + rows0 + off) = v;
  }
}

// ---------------------------------------------------------------------------
extern "C" void kernel_launch(void* const* d_in, const int* in_sizes, int n_in,
                              void* d_out, int out_size, void* d_ws, size_t ws_size,
                              hipStream_t stream) {
  (void)in_sizes; (void)n_in; (void)out_size; (void)ws_size;
  const float* r     = (const float*)d_in[0];
  const float* embed = (const float*)d_in[1];
  const float* wfilt = (const float*)d_in[2];
  const float* w1    = (const float*)d_in[3];
  const float* b1    = (const float*)d_in[4];
  const float* w2    = (const float*)d_in[5];
  const float* b2    = (const float*)d_in[6];

  char* ws = (char*)d_ws;
  size_t off = 0;
  auto alloc = [&](size_t bytes) {
    void* p = ws + off; off += (bytes + 255) & ~(size_t)255; return p;
  };
  unsigned short* A2   = (unsigned short*)alloc((size_t)NN * KK * NN * 2);  // 33.5 MB
  unsigned short* hTa  = (unsigned short*)alloc((size_t)DD * NN * 2);
  unsigned short* hTb  = (unsigned short*)alloc((size_t)DD * NN * 2);
  unsigned short* w1T  = (unsigned short*)alloc((size_t)DD * 384 * 2);
  unsigned short* w2T  = (unsigned short*)alloc((size_t)DD * 384 * 2);
  float* AGG = (float*)alloc((size_t)SPLITK * NN * DD * 4);
  float* hb  = (float*)alloc((size_t)NN * DD * 4);
  int*   CNT = (int*)alloc(192 * 4);

  edge_setup<<<4096 + 57, 256, 0, stream>>>(r, embed, w1, w2, A2, hTa, w1T, w2T, CNT);

  for (int l = 0; l < 3; ++l) {
    bool fin = (l == 2);
    const unsigned short* htin  = (l & 1) ? hTb : hTa;
    unsigned short*       htout = (l & 1) ? hTa : hTb;
    gemm_fused<<<128 * SPLITK, 256, 0, stream>>>(
        A2, htin, wfilt + (size_t)l * KK * DD, AGG, CNT + l * 64,
        (l == 0) ? embed : hb,
        w1T + (size_t)l * DD, b1 + (size_t)l * DD,
        w2T + (size_t)l * DD, b2 + (size_t)l * DD,
        fin ? nullptr : hb, fin ? nullptr : htout,
        fin ? (float*)d_out : nullptr);
  }
}

// Round 6
// 86.380 us; speedup vs baseline: 5.1531x; 5.1531x over previous
//
#include <hip/hip_runtime.h>
#include <hip/hip_bf16.h>

#define NN 1024
#define DD 128
#define KK 16
#define SPLITK 8

typedef __attribute__((ext_vector_type(4))) float f32x4;
typedef __attribute__((ext_vector_type(8))) short bf16x8;
typedef __attribute__((ext_vector_type(4))) unsigned int u32x4;
typedef __attribute__((ext_vector_type(4))) unsigned short u16x4;

static __device__ __forceinline__ unsigned short f2bf(float x) {
  union { __hip_bfloat16 h; unsigned short u; } v;
  v.h = __float2bfloat16(x);
  return v.u;
}

// ---------------------------------------------------------------------------
// Kernel 1: edge features -> A2[(i*16+k)][j] = rbf(i,j,k)*w(i,j)  (bf16)
// plus tail blocks: transpose-cast embed->hT, w1->w1T, w2->w2T
// ---------------------------------------------------------------------------
__global__ __launch_bounds__(256) void edge_setup(
    const float* __restrict__ r, const float* __restrict__ embed,
    const float* __restrict__ w1, const float* __restrict__ w2,
    unsigned short* __restrict__ A2, unsigned short* __restrict__ hT,
    unsigned short* __restrict__ w1T, unsigned short* __restrict__ w2T)
{
  int b = blockIdx.x;
  if (b < 4096) {
    int idx = b * 256 + threadIdx.x;
    int i = idx >> 10, j = idx & (NN - 1);
    float dx = r[i*3+0] - r[j*3+0];
    float dy = r[i*3+1] - r[j*3+1];
    float dz = r[i*3+2] - r[j*3+2];
    float d2 = dx*dx + dy*dy + dz*dz;
    float vals[KK];
    bool on = (i != j) && (d2 < 4.0f);
    if (on) {
      float dist = sqrtf(d2);
      float w  = 0.5f * (__cosf(1.57079632679f * dist) + 1.0f);  // cos(pi*d/2)
      float E0 = __expf(-10.0f * d2);
      float q  = __expf(2.66666667f * dist);      // exp(20*(2/15)*d)
      float u  = __expf(-0.17777778f);            // exp(-10*(2/15)^2)
      float u2 = u * u;
      float p = 1.0f, c = 1.0f, s = u;
      #pragma unroll
      for (int k = 0; k < KK; ++k) {
        vals[k] = w * (E0 * p) * c;   // = w * exp(-10*(d - k*2/15)^2)
        p *= q;
        c *= s;
        s *= u2;
      }
    } else {
      #pragma unroll
      for (int k = 0; k < KK; ++k) vals[k] = 0.0f;
    }
    #pragma unroll
    for (int k = 0; k < KK; ++k)
      A2[(size_t)(i * KK + k) * NN + j] = f2bf(vals[k]);
  } else {
    // transpose-cast jobs, 64x64 tiles via LDS
    int t = b - 4096;
    const float* src; unsigned short* dst; int R, r0, c0;
    if (t < 32)      { src = embed; dst = hT;  R = NN;  int u = t;      r0 = (u>>1)*64; c0 = (u&1)*64; }
    else if (t < 44) { src = w1;    dst = w1T; R = 384; int u = t - 32; r0 = (u>>1)*64; c0 = (u&1)*64; }
    else             { src = w2;    dst = w2T; R = 384; int u = t - 44; r0 = (u>>1)*64; c0 = (u&1)*64; }
    __shared__ float Ls[64][65];
    #pragma unroll
    for (int it = 0; it < 16; ++it) {
      int idx = it * 256 + threadIdx.x;
      int rr = idx >> 6, cc = idx & 63;
      Ls[rr][cc] = src[(size_t)(r0 + rr) * DD + c0 + cc];
    }
    __syncthreads();
    #pragma unroll
    for (int it = 0; it < 16; ++it) {
      int idx = it * 256 + threadIdx.x;
      int oc = idx >> 6, orr = idx & 63;       // out row = c0+oc, out col = r0+orr
      dst[(size_t)(c0 + oc) * R + r0 + orr] = f2bf(Ls[orr][oc]);
    }
  }
}

// ---------------------------------------------------------------------------
// Kernel 2: T = A2 @ H  (M=16384, N=128, K=1024), fused w_filt epilogue.
// Grid 1024 = 128 M-tiles x split-K 8 (j-range 128 each).
// SINGLE-SHOT staging: 16 independent u32x4 loads/thread -> regs -> LDS,
// ONE barrier, then 64 MFMAs back-to-back. 2 WGs/CU (LDS 68 KB).
// ---------------------------------------------------------------------------
__global__ __launch_bounds__(256, 2) void gemm_agg(
    const unsigned short* __restrict__ A2, const unsigned short* __restrict__ hT,
    const float* __restrict__ wf,            // layer slice [16][128]
    float* __restrict__ aggbase)             // SPLITK planes of [1024][128]
{
  __shared__ unsigned short As[128][136];    // 128 m-rows x 128 j (+8 pad)
  __shared__ unsigned short Bs[128][136];    // 128 d-rows x 128 j (+8 pad)
  int wg = blockIdx.x;
  int mt = wg >> 3;                          // 0..127
  int ks = wg & 7;
  int mbase = mt * 128;
  int jbase = ks * 128;
  int tid = threadIdx.x;
  int w = tid >> 6, lane = tid & 63;
  int wm = w >> 1, wd = w & 1;
  int lg = lane >> 4, l16 = lane & 15;

  // ---- stage: issue all 16 loads (deep MLP), then write LDS, one barrier ----
  u32x4 va[8], vb[8];
  #pragma unroll
  for (int it = 0; it < 8; ++it) {
    int c = tid + it * 256;                  // 0..2047
    int row = c >> 4, sh = (c & 15) * 8;     // 16 chunks of 8 shorts per row
    va[it] = *(const u32x4*)(A2 + (size_t)(mbase + row) * NN + jbase + sh);
    vb[it] = *(const u32x4*)(hT + (size_t)row * NN + jbase + sh);
  }
  #pragma unroll
  for (int it = 0; it < 8; ++it) {
    int c = tid + it * 256;
    int row = c >> 4, sh = (c & 15) * 8;
    *(u32x4*)(&As[row][sh]) = va[it];
    *(u32x4*)(&Bs[row][sh]) = vb[it];
  }
  __syncthreads();

  // ---- compute: 4 K-steps x 16 MFMA ----
  f32x4 acc[4][4];
  #pragma unroll
  for (int a = 0; a < 4; ++a)
    #pragma unroll
    for (int bq = 0; bq < 4; ++bq) acc[a][bq] = (f32x4){0.f, 0.f, 0.f, 0.f};

  #pragma unroll
  for (int kk = 0; kk < 4; ++kk) {
    bf16x8 af[4], bfr[4];
    #pragma unroll
    for (int f = 0; f < 4; ++f) {
      af[f]  = *(const bf16x8*)(&As[wm*64 + f*16 + l16][kk*32 + lg*8]);
      bfr[f] = *(const bf16x8*)(&Bs[wd*64 + f*16 + l16][kk*32 + lg*8]);
    }
    #pragma unroll
    for (int fm = 0; fm < 4; ++fm)
      #pragma unroll
      for (int fd = 0; fd < 4; ++fd)
        acc[fm][fd] = __builtin_amdgcn_mfma_f32_16x16x32_bf16(
            af[fm], bfr[fd], acc[fm][fd], 0, 0, 0);
  }

  // epilogue: agg_partial[node][d] = sum_k wf[k][d] * T[(node,k)][d]
  float* aggp = aggbase + (size_t)ks * NN * DD;
  float wfv[4][4];
  #pragma unroll
  for (int fd = 0; fd < 4; ++fd) {
    int d = wd*64 + fd*16 + l16;
    #pragma unroll
    for (int rr = 0; rr < 4; ++rr)
      wfv[fd][rr] = wf[(lg*4 + rr) * DD + d];
  }
  #pragma unroll
  for (int fm = 0; fm < 4; ++fm) {
    int node = mt * 8 + wm * 4 + fm;
    #pragma unroll
    for (int fd = 0; fd < 4; ++fd) {
      int d = wd*64 + fd*16 + l16;
      float sum = 0.f;
      #pragma unroll
      for (int rr = 0; rr < 4; ++rr)
        sum += acc[fm][fd][rr] * wfv[fd][rr];
      sum += __shfl_xor(sum, 16, 64);
      sum += __shfl_xor(sum, 32, 64);
      if (lg == 0) aggp[(size_t)node * DD + d] = sum;
    }
  }
}

// ---------------------------------------------------------------------------
// Kernel 3: node MLP. 64 WGs x 16 rows. Sums SPLITK agg planes, casts bf16,
// GEMM1 (@w1T) -> +b1 -> silu -> GEMM2 (@w2T) -> +b2 + residual.
// Non-final: writes hbuf f32 (in-place safe, same-thread map) + hT bf16.
// Final: writes d_out f32.
// ---------------------------------------------------------------------------
__global__ __launch_bounds__(256) void mlp(
    const float* __restrict__ aggbase,
    const float* __restrict__ hprev,
    const unsigned short* __restrict__ w1T,  // col-offset by layer, row stride 384
    const float* __restrict__ b1,
    const unsigned short* __restrict__ w2T,
    const float* __restrict__ b2,
    float* __restrict__ hnext,
    unsigned short* __restrict__ hTnext,
    float* __restrict__ outf)
{
  __shared__ unsigned short Xs[16][136];
  __shared__ unsigned short Ws[128][136];
  int tid = threadIdx.x, w = tid >> 6, lane = tid & 63;
  int lg = lane >> 4, l16 = lane & 15;
  int rows0 = blockIdx.x * 16;

  // stage X = bf16(sum of SPLITK agg planes): 16x128
  #pragma unroll
  for (int it = 0; it < 2; ++it) {
    int c = tid + it * 256;                   // 512 chunks of 4 floats
    int row = c >> 5, off = (c & 31) * 4;
    size_t g = (size_t)(rows0 + row) * DD + off;
    f32x4 s0 = *(const f32x4*)(aggbase + g);
    #pragma unroll
    for (int p = 1; p < SPLITK; ++p) {
      f32x4 vp = *(const f32x4*)(aggbase + (size_t)p * NN * DD + g);
      s0 += vp;
    }
    u16x4 t4;
    #pragma unroll
    for (int e = 0; e < 4; ++e) t4[e] = f2bf(s0[e]);
    *(u16x4*)(&Xs[row][off]) = t4;
  }
  // stage W1: 128x128
  #pragma unroll
  for (int it = 0; it < 8; ++it) {
    int c = tid + it * 256;
    int row = c >> 4, off8 = (c & 15) * 8;
    u32x4 v = *(const u32x4*)(w1T + (size_t)row * 384 + off8);
    *(u32x4*)(&Ws[row][off8]) = v;
  }
  __syncthreads();

  // GEMM1: wave w -> out cols [w*32, w*32+32)
  f32x4 acc1[2];
  acc1[0] = (f32x4){0.f,0.f,0.f,0.f}; acc1[1] = (f32x4){0.f,0.f,0.f,0.f};
  #pragma unroll
  for (int s = 0; s < 4; ++s) {
    bf16x8 a = *(const bf16x8*)(&Xs[l16][s*32 + lg*8]);
    #pragma unroll
    for (int f = 0; f < 2; ++f) {
      bf16x8 bb = *(const bf16x8*)(&Ws[(w*2+f)*16 + l16][s*32 + lg*8]);
      acc1[f] = __builtin_amdgcn_mfma_f32_16x16x32_bf16(a, bb, acc1[f], 0, 0, 0);
    }
  }
  __syncthreads();   // all GEMM1 LDS reads done

  // silu -> Xs (overwrite), restage W2 -> Ws
  #pragma unroll
  for (int f = 0; f < 2; ++f) {
    int d = w*32 + f*16 + l16;
    float bb1 = b1[d];
    #pragma unroll
    for (int rr = 0; rr < 4; ++rr) {
      float x = acc1[f][rr] + bb1;
      float sv = x / (1.0f + __expf(-x));
      Xs[lg*4 + rr][d] = f2bf(sv);
    }
  }
  #pragma unroll
  for (int it = 0; it < 8; ++it) {
    int c = tid + it * 256;
    int row = c >> 4, off8 = (c & 15) * 8;
    u32x4 v = *(const u32x4*)(w2T + (size_t)row * 384 + off8);
    *(u32x4*)(&Ws[row][off8]) = v;
  }
  __syncthreads();

  // GEMM2
  f32x4 acc2[2];
  acc2[0] = (f32x4){0.f,0.f,0.f,0.f}; acc2[1] = (f32x4){0.f,0.f,0.f,0.f};
  #pragma unroll
  for (int s = 0; s < 4; ++s) {
    bf16x8 a = *(const bf16x8*)(&Xs[l16][s*32 + lg*8]);
    #pragma unroll
    for (int f = 0; f < 2; ++f) {
      bf16x8 bb = *(const bf16x8*)(&Ws[(w*2+f)*16 + l16][s*32 + lg*8]);
      acc2[f] = __builtin_amdgcn_mfma_f32_16x16x32_bf16(a, bb, acc2[f], 0, 0, 0);
    }
  }

  // epilogue: v = acc2 + b2 + hprev
  float vv[2][4];
  bool fin = (outf != nullptr);
  #pragma unroll
  for (int f = 0; f < 2; ++f) {
    int d = w*32 + f*16 + l16;
    float bb2 = b2[d];
    #pragma unroll
    for (int rr = 0; rr < 4; ++rr) {
      int row = rows0 + lg*4 + rr;
      float v = acc2[f][rr] + bb2 + hprev[(size_t)row * DD + d];
      vv[f][rr] = v;
      if (fin) outf[(size_t)row * DD + d] = v;
      else     hnext[(size_t)row * DD + d] = v;
    }
  }
  if (!fin) {
    __syncthreads();   // GEMM2 LDS reads done before Ws reuse
    // transposed tile into Ws: [d][m_local 0..15]
    #pragma unroll
    for (int f = 0; f < 2; ++f) {
      int d = w*32 + f*16 + l16;
      #pragma unroll
      for (int rr = 0; rr < 4; ++rr)
        Ws[d][lg*4 + rr] = f2bf(vv[f][rr]);
    }
    __syncthreads();
    // copy out: hT[d][rows0..+16], one u32x4 per thread (256 thr = 128 rows x 2)
    int d = tid >> 1, off = (tid & 1) * 8;
    u32x4 v = *(const u32x4*)(&Ws[d][off]);
    *(u32x4*)(hTnext + (size_t)d * NN + rows0 + off) = v;
  }
}

// ---------------------------------------------------------------------------
extern "C" void kernel_launch(void* const* d_in, const int* in_sizes, int n_in,
                              void* d_out, int out_size, void* d_ws, size_t ws_size,
                              hipStream_t stream) {
  (void)in_sizes; (void)n_in; (void)out_size; (void)ws_size;
  const float* r     = (const float*)d_in[0];
  const float* embed = (const float*)d_in[1];
  const float* wfilt = (const float*)d_in[2];
  const float* w1    = (const float*)d_in[3];
  const float* b1    = (const float*)d_in[4];
  const float* w2    = (const float*)d_in[5];
  const float* b2    = (const float*)d_in[6];

  char* ws = (char*)d_ws;
  size_t off = 0;
  auto alloc = [&](size_t bytes) {
    void* p = ws + off; off += (bytes + 255) & ~(size_t)255; return p;
  };
  unsigned short* A2   = (unsigned short*)alloc((size_t)NN * KK * NN * 2);  // 33.5 MB
  unsigned short* hT   = (unsigned short*)alloc((size_t)DD * NN * 2);
  unsigned short* w1T  = (unsigned short*)alloc((size_t)DD * 384 * 2);
  unsigned short* w2T  = (unsigned short*)alloc((size_t)DD * 384 * 2);
  float* AGG = (float*)alloc((size_t)SPLITK * NN * DD * 4);
  float* hb  = (float*)alloc((size_t)NN * DD * 4);

  edge_setup<<<4096 + 56, 256, 0, stream>>>(r, embed, w1, w2, A2, hT, w1T, w2T);

  const float* hp = embed;
  for (int l = 0; l < 3; ++l) {
    gemm_agg<<<128 * SPLITK, 256, 0, stream>>>(A2, hT, wfilt + (size_t)l * KK * DD, AGG);
    bool fin = (l == 2);
    mlp<<<64, 256, 0, stream>>>(AGG, hp,
        w1T + (size_t)l * DD, b1 + (size_t)l * DD,
        w2T + (size_t)l * DD, b2 + (size_t)l * DD,
        fin ? nullptr : hb, fin ? nullptr : hT,
        fin ? (float*)d_out : nullptr);
    hp = hb;
  }
}